// Round 9
// baseline (252.247 us; speedup 1.0000x reference)
//
#include <hip/hip_runtime.h>
#include <math.h>
#include <stdint.h>

#define D 128          // feature dim (d_in = d_h = 128)
#define SCAN_CHUNK 2048
#define LDA 136        // LDS row stride in shorts (+8 pad: 16-way -> 2-way bank conflict)

typedef __attribute__((ext_vector_type(8))) short v8s;   // 8 bf16 (4 VGPRs)
typedef __attribute__((ext_vector_type(4))) float v4f;   // MFMA accumulator

// bf16 round-to-nearest-even
static __device__ __forceinline__ uint16_t f2bf(float f) {
    uint32_t u = __float_as_uint(f);
    u = (u + 0x7fff + ((u >> 16) & 1)) >> 16;
    return (uint16_t)u;
}
static __device__ __forceinline__ float bf2f(uint16_t h) { return __uint_as_float((uint32_t)h << 16); }
static __device__ __forceinline__ float bf_lo(uint32_t u) { return __uint_as_float(u << 16); }
static __device__ __forceinline__ float bf_hi(uint32_t u) { return __uint_as_float(u & 0xffff0000u); }

// ---------------- count + rank + W-pack (fused, independent work) ----------------
// rank[e] = edge's slot within its target bucket (atomicAdd return) -> fill has NO atomics.

__global__ void countpack_kernel(const int* __restrict__ col, int* __restrict__ cnt,
                                 int* __restrict__ rnk, int E,
                                 const float* __restrict__ W1, const float* __restrict__ W2,
                                 uint16_t* __restrict__ Wh, uint16_t* __restrict__ Wl) {
    int tid = blockIdx.x * blockDim.x + threadIdx.x;
    if (tid < 2 * 16384) {
        int layer = tid >> 14;
        int li = tid & 16383;
        int j = li & 7, lane = (li >> 3) & 63, f = li >> 9;
        int kstep = f >> 3, tile = f & 7;
        int k = kstep * 32 + ((lane >> 4) * 8) + j;
        int nn = tile * 16 + (lane & 15);
        const float* W = layer ? W2 : W1;
        float v = W[k * 128 + nn];
        uint16_t h = f2bf(v);
        Wh[tid] = h;
        Wl[tid] = f2bf(v - bf2f(h));
    }
    if (tid < E) rnk[tid] = atomicAdd(&cnt[col[tid]], 1);
}

// ---------------- scan phase A: per-chunk sums (+ fused dinv) ----------------
// Multi-block, coalesced. (Single-block variant measured 134 us @0.17% occupancy — do not revisit.)

__global__ __launch_bounds__(256) void scanA_kernel(const int* __restrict__ cnt,
                                                    int* __restrict__ bsum,
                                                    float* __restrict__ dinv, int n) {
    __shared__ int wsum[4];
    int b = blockIdx.x, t = threadIdx.x;
    int base = b * SCAN_CHUNK;
    int s = 0;
#pragma unroll
    for (int k = 0; k < SCAN_CHUNK / 256; k++) {
        int i = base + k * 256 + t;
        if (i < n) {
            int c = cnt[i];
            s += c;
            dinv[i] = rsqrtf((float)c + 1.0f);
        }
    }
#pragma unroll
    for (int off = 32; off > 0; off >>= 1) s += __shfl_xor(s, off, 64);
    if ((t & 63) == 0) wsum[t >> 6] = s;
    __syncthreads();
    if (t == 0) bsum[b] = wsum[0] + wsum[1] + wsum[2] + wsum[3];
}

// ---------------- scan phase C: local exclusive scan, block bases inlined ----------------

__global__ __launch_bounds__(256) void scanC_kernel(const int* __restrict__ cnt,
                                                    const int* __restrict__ bsum,
                                                    int* __restrict__ offs, int n, int nb) {
    __shared__ int stage[SCAN_CHUNK];
    __shared__ int res[SCAN_CHUNK];
    __shared__ int tsum[256];
    __shared__ int sb[64];
    int b = blockIdx.x, t = threadIdx.x;
    if (t < 64) {
        int v = (t < nb) ? bsum[t] : 0;
        int inc = v;
#pragma unroll
        for (int off = 1; off < 64; off <<= 1) {
            int u = __shfl_up(inc, off, 64);
            if (t >= off) inc += u;
        }
        sb[t] = inc;
    }
    int base = b * SCAN_CHUNK;
#pragma unroll
    for (int k = 0; k < SCAN_CHUNK / 256; k++) {
        int i = base + k * 256 + t;
        stage[k * 256 + t] = (i < n) ? cnt[i] : 0;
    }
    __syncthreads();
    int my = 0;
#pragma unroll
    for (int j = 0; j < 8; j++) my += stage[t * 8 + j];
    tsum[t] = my;
    __syncthreads();
    for (int off = 1; off < 256; off <<= 1) {
        int v = (t >= off) ? tsum[t - off] : 0;
        __syncthreads();
        tsum[t] += v;
        __syncthreads();
    }
    int bbase = (b == 0) ? 0 : sb[b - 1];
    int run = tsum[t] - my + bbase;
#pragma unroll
    for (int j = 0; j < 8; j++) {
        res[t * 8 + j] = run;
        run += stage[t * 8 + j];
    }
    __syncthreads();
#pragma unroll
    for (int k = 0; k < SCAN_CHUNK / 256; k++) {
        int i = base + k * 256 + t;
        if (i < n) offs[i] = res[k * 256 + t];
    }
    if (b == gridDim.x - 1 && t == 0) offs[n] = sb[nb - 1];
}

// ---------------- MFMA GEMM body (4 waves, flat [M][128] bf16 C-write) ----------------
// split-bf16 (Markidis): A@W ~= Ah@Wh + Ah@Wl + Al@Wh; result pre-scaled by dinv.

static __device__ __forceinline__ void gemm_body(const uint16_t Ah[][LDA],
                                                 const uint16_t Al[][LDA],
                                                 const uint16_t* __restrict__ Wph,
                                                 const uint16_t* __restrict__ Wpl,
                                                 const float* __restrict__ dinv,
                                                 uint16_t* __restrict__ Cb,
                                                 int base_row, int M, int t) {
    int lane = t & 63, w = t >> 6;
    int m_l = lane & 15, quad = lane >> 4;
    int arow = w * 16 + m_l;

    v4f acc[8];
#pragma unroll
    for (int i = 0; i < 8; i++) acc[i] = (v4f){0.f, 0.f, 0.f, 0.f};

#pragma unroll
    for (int ks = 0; ks < 4; ks++) {
        v8s ah = *(const v8s*)&Ah[arow][ks * 32 + quad * 8];
        v8s al = *(const v8s*)&Al[arow][ks * 32 + quad * 8];
#pragma unroll
        for (int ti = 0; ti < 8; ti++) {
            int f = ks * 8 + ti;
            v8s bh = *(const v8s*)(Wph + ((size_t)(f * 64 + lane)) * 8);
            v8s bl = *(const v8s*)(Wpl + ((size_t)(f * 64 + lane)) * 8);
            acc[ti] = __builtin_amdgcn_mfma_f32_16x16x32_bf16(al, bh, acc[ti], 0, 0, 0);
            acc[ti] = __builtin_amdgcn_mfma_f32_16x16x32_bf16(ah, bl, acc[ti], 0, 0, 0);
            acc[ti] = __builtin_amdgcn_mfma_f32_16x16x32_bf16(ah, bh, acc[ti], 0, 0, 0);
        }
    }

    int rbase = base_row + w * 16 + quad * 4;
#pragma unroll
    for (int reg = 0; reg < 4; reg++) {
        int gr = rbase + reg;
        if (gr < M) {
            float di = dinv[gr];
#pragma unroll
            for (int ti = 0; ti < 8; ti++) {
                Cb[(size_t)gr * D + ti * 16 + m_l] = f2bf(di * acc[ti][reg]);
            }
        }
    }
}

// f32 [M][128] row-major A-tile -> split-bf16 LDS staging (shared by both GEMMs)
static __device__ __forceinline__ void stage_tile(uint16_t Ah[][LDA], uint16_t Al[][LDA],
                                                  const float* __restrict__ A,
                                                  int base_row, int M, int t) {
#pragma unroll
    for (int kk = 0; kk < 8; kk++) {
        int idx = kk * 256 + t;
        int r = idx >> 5;
        int c4 = idx & 31;
        int gr = base_row + r;
        float4 f = (gr < M) ? *(const float4*)(A + (size_t)gr * D + c4 * 4)
                            : make_float4(0.f, 0.f, 0.f, 0.f);
        uint16_t h0 = f2bf(f.x), h1 = f2bf(f.y), h2 = f2bf(f.z), h3 = f2bf(f.w);
        uint16_t l0 = f2bf(f.x - bf2f(h0)), l1 = f2bf(f.y - bf2f(h1));
        uint16_t l2 = f2bf(f.z - bf2f(h2)), l3 = f2bf(f.w - bf2f(h3));
        *(ushort4*)&Ah[r][c4 * 4] = make_ushort4(h0, h1, h2, h3);
        *(ushort4*)&Al[r][c4 * 4] = make_ushort4(l0, l1, l2, l3);
    }
}

// ---------------- fused: CSR fill (block-role split) + layer-1 GEMM ----------------

__global__ __launch_bounds__(256) void fillgemm_kernel(const int* __restrict__ row,
                                                       const int* __restrict__ col,
                                                       const int* __restrict__ rnk,
                                                       const int* __restrict__ offs,
                                                       int* __restrict__ adj, int E,
                                                       const float* __restrict__ A,
                                                       const uint16_t* __restrict__ Wph,
                                                       const uint16_t* __restrict__ Wpl,
                                                       const float* __restrict__ dinv,
                                                       uint16_t* __restrict__ Cb, int M,
                                                       int nbG) {
    __shared__ uint16_t Ah[64][LDA];
    __shared__ uint16_t Al[64][LDA];
    int t = threadIdx.x;

    if (blockIdx.x >= nbG) {   // ---- fill role (atomic-free scatter) ----
        int e = (blockIdx.x - nbG) * 256 + t;
        if (e < E) adj[offs[col[e]] + rnk[e]] = row[e];
        return;
    }

    int base_row = blockIdx.x * 64;
    stage_tile(Ah, Al, A, base_row, M, t);
    __syncthreads();
    gemm_body(Ah, Al, Wph, Wpl, dinv, Cb, base_row, M, t);
}

// ---------------- plain GEMM (layer 2: h -> xwb2) ----------------

__global__ __launch_bounds__(256) void gemm_kernel(const float* __restrict__ A,
                                                   const uint16_t* __restrict__ Wph,
                                                   const uint16_t* __restrict__ Wpl,
                                                   const float* __restrict__ dinv,
                                                   uint16_t* __restrict__ Cb, int M) {
    __shared__ uint16_t Ah[64][LDA];
    __shared__ uint16_t Al[64][LDA];
    int t = threadIdx.x;
    int base_row = blockIdx.x * 64;
    stage_tile(Ah, Al, A, base_row, M, t);
    __syncthreads();
    gemm_body(Ah, Al, Wph, Wpl, dinv, Cb, base_row, M, t);
}

// ---------------- gather helpers (full-row uint32: one 256 B row per wave-load) ------

static __device__ __forceinline__ void drain1(const uint32_t* __restrict__ xwb,
                                              const int* __restrict__ adj, int lane,
                                              int& j, int e, float& x0, float& x1) {
    for (; j + 7 < e; j += 8) {
        int xx[8]; uint32_t u[8];
#pragma unroll
        for (int q = 0; q < 8; q++) xx[q] = adj[j + q];
#pragma unroll
        for (int q = 0; q < 8; q++) u[q] = xwb[(size_t)xx[q] * (D / 2) + lane];
#pragma unroll
        for (int q = 0; q < 8; q++) { x0 += bf_lo(u[q]); x1 += bf_hi(u[q]); }
    }
    for (; j + 3 < e; j += 4) {
        int xx[4]; uint32_t u[4];
#pragma unroll
        for (int q = 0; q < 4; q++) xx[q] = adj[j + q];
#pragma unroll
        for (int q = 0; q < 4; q++) u[q] = xwb[(size_t)xx[q] * (D / 2) + lane];
#pragma unroll
        for (int q = 0; q < 4; q++) { x0 += bf_lo(u[q]); x1 += bf_hi(u[q]); }
    }
    for (; j < e; j++) {
        uint32_t u = xwb[(size_t)adj[j] * (D / 2) + lane];
        x0 += bf_lo(u); x1 += bf_hi(u);
    }
}

static __device__ __forceinline__ void drain2(const uint32_t* __restrict__ xwb,
                                              const int* __restrict__ adj, int lane,
                                              int& jA, int eA, float& x0, float& x1,
                                              int& jB, int eB, float& y0, float& y1) {
    while (jA + 7 < eA && jB + 7 < eB) {
        int xx[8], yy[8];
#pragma unroll
        for (int q = 0; q < 8; q++) { xx[q] = adj[jA + q]; yy[q] = adj[jB + q]; }
        uint32_t uA[8], uB[8];
#pragma unroll
        for (int q = 0; q < 8; q++) {
            uA[q] = xwb[(size_t)xx[q] * (D / 2) + lane];
            uB[q] = xwb[(size_t)yy[q] * (D / 2) + lane];
        }
#pragma unroll
        for (int q = 0; q < 8; q++) {
            x0 += bf_lo(uA[q]); x1 += bf_hi(uA[q]);
            y0 += bf_lo(uB[q]); y1 += bf_hi(uB[q]);
        }
        jA += 8; jB += 8;
    }
}

// ---------------- aggregation, layer 1: THREE nodes per wave ----------
// Triple-interleaved 8-deep main loop -> 24 row-loads (96 lines) in flight per wave
// (R8's 2-node/16-load form measured best of six gather variants; MLP is the live
// axis: R4 occupancy-doubling = no change, R7->R8 MLP-deepening = +4.6%).

__global__ __launch_bounds__(256) void agg1_kernel(const uint32_t* __restrict__ xwb,
                                                   const int* __restrict__ adj,
                                                   const int* __restrict__ offs,
                                                   const float* __restrict__ dinv,
                                                   const float* __restrict__ bias,
                                                   float* __restrict__ hout, int n) {
    int wave = (int)((blockIdx.x * (size_t)blockDim.x + threadIdx.x) >> 6);
    int lane = threadIdx.x & 63;
    int i0 = wave * 3, i1 = i0 + 1, i2 = i0 + 2;
    if (i0 >= n) return;
    bool has1 = (i1 < n), has2 = (i2 < n);

    float a0, a1, c0 = 0.f, c1 = 0.f, d0 = 0.f, d1 = 0.f;
    uint32_t su0 = xwb[(size_t)i0 * (D / 2) + lane];
    a0 = bf_lo(su0); a1 = bf_hi(su0);
    int jA = offs[i0], eA = offs[i0 + 1];
    int jB = 0, eB = 0, jC = 0, eC = 0;
    if (has1) {
        uint32_t su1 = xwb[(size_t)i1 * (D / 2) + lane];
        c0 = bf_lo(su1); c1 = bf_hi(su1);
        jB = offs[i1]; eB = offs[i1 + 1];
    }
    if (has2) {
        uint32_t su2 = xwb[(size_t)i2 * (D / 2) + lane];
        d0 = bf_lo(su2); d1 = bf_hi(su2);
        jC = offs[i2]; eC = offs[i2 + 1];
    }

    // triple-interleaved main loop: 24 rows in flight
    while (jA + 7 < eA && jB + 7 < eB && jC + 7 < eC) {
        int xx[8], yy[8], zz[8];
#pragma unroll
        for (int q = 0; q < 8; q++) { xx[q] = adj[jA + q]; yy[q] = adj[jB + q]; zz[q] = adj[jC + q]; }
        uint32_t uA[8], uB[8], uC[8];
#pragma unroll
        for (int q = 0; q < 8; q++) {
            uA[q] = xwb[(size_t)xx[q] * (D / 2) + lane];
            uB[q] = xwb[(size_t)yy[q] * (D / 2) + lane];
            uC[q] = xwb[(size_t)zz[q] * (D / 2) + lane];
        }
#pragma unroll
        for (int q = 0; q < 8; q++) {
            a0 += bf_lo(uA[q]); a1 += bf_hi(uA[q]);
            c0 += bf_lo(uB[q]); c1 += bf_hi(uB[q]);
            d0 += bf_lo(uC[q]); d1 += bf_hi(uC[q]);
        }
        jA += 8; jB += 8; jC += 8;
    }
    // pairwise drains (16 in flight), then singles
    drain2(xwb, adj, lane, jA, eA, a0, a1, jB, eB, c0, c1);
    drain2(xwb, adj, lane, jA, eA, a0, a1, jC, eC, d0, d1);
    drain2(xwb, adj, lane, jB, eB, c0, c1, jC, eC, d0, d1);
    drain1(xwb, adj, lane, jA, eA, a0, a1);
    drain1(xwb, adj, lane, jB, eB, c0, c1);
    drain1(xwb, adj, lane, jC, eC, d0, d1);

    float2 bv = ((const float2*)bias)[lane];
    float di0 = dinv[i0];
    ((float2*)(hout + (size_t)i0 * D))[lane] =
        make_float2(fmaxf(fmaf(di0, a0, bv.x), 0.f), fmaxf(fmaf(di0, a1, bv.y), 0.f));
    if (has1) {
        float di1 = dinv[i1];
        ((float2*)(hout + (size_t)i1 * D))[lane] =
            make_float2(fmaxf(fmaf(di1, c0, bv.x), 0.f), fmaxf(fmaf(di1, c1, bv.y), 0.f));
    }
    if (has2) {
        float di2 = dinv[i2];
        ((float2*)(hout + (size_t)i2 * D))[lane] =
            make_float2(fmaxf(fmaf(di2, d0, bv.x), 0.f), fmaxf(fmaf(di2, d1, bv.y), 0.f));
    }
}

// ---------------- layer-2 aggregation + classifier precompute, THREE nodes per wave --
// Same gather; epilogue computes all three nodes' 8 classifier dot-products in-register
// and reduces 24 values with one 6-stage butterfly (48 shuffles/node, same as 2-node).

__global__ __launch_bounds__(256) void agg2pq_kernel(const uint32_t* __restrict__ xwb,
                                                     const int* __restrict__ adj,
                                                     const int* __restrict__ offs,
                                                     const float* __restrict__ dinv,
                                                     const float* __restrict__ bias,
                                                     const float* __restrict__ Wfc,
                                                     const float* __restrict__ bfc,
                                                     float* __restrict__ P1,
                                                     float* __restrict__ P2, int n) {
    int wave = (int)((blockIdx.x * (size_t)blockDim.x + threadIdx.x) >> 6);
    int lane = threadIdx.x & 63;
    int i0 = wave * 3, i1 = i0 + 1, i2 = i0 + 2;
    if (i0 >= n) return;
    bool has1 = (i1 < n), has2 = (i2 < n);

    float a0, a1, c0 = 0.f, c1 = 0.f, d0 = 0.f, d1 = 0.f;
    uint32_t su0 = xwb[(size_t)i0 * (D / 2) + lane];
    a0 = bf_lo(su0); a1 = bf_hi(su0);
    int jA = offs[i0], eA = offs[i0 + 1];
    int jB = 0, eB = 0, jC = 0, eC = 0;
    if (has1) {
        uint32_t su1 = xwb[(size_t)i1 * (D / 2) + lane];
        c0 = bf_lo(su1); c1 = bf_hi(su1);
        jB = offs[i1]; eB = offs[i1 + 1];
    }
    if (has2) {
        uint32_t su2 = xwb[(size_t)i2 * (D / 2) + lane];
        d0 = bf_lo(su2); d1 = bf_hi(su2);
        jC = offs[i2]; eC = offs[i2 + 1];
    }

    while (jA + 7 < eA && jB + 7 < eB && jC + 7 < eC) {
        int xx[8], yy[8], zz[8];
#pragma unroll
        for (int q = 0; q < 8; q++) { xx[q] = adj[jA + q]; yy[q] = adj[jB + q]; zz[q] = adj[jC + q]; }
        uint32_t uA[8], uB[8], uC[8];
#pragma unroll
        for (int q = 0; q < 8; q++) {
            uA[q] = xwb[(size_t)xx[q] * (D / 2) + lane];
            uB[q] = xwb[(size_t)yy[q] * (D / 2) + lane];
            uC[q] = xwb[(size_t)zz[q] * (D / 2) + lane];
        }
#pragma unroll
        for (int q = 0; q < 8; q++) {
            a0 += bf_lo(uA[q]); a1 += bf_hi(uA[q]);
            c0 += bf_lo(uB[q]); c1 += bf_hi(uB[q]);
            d0 += bf_lo(uC[q]); d1 += bf_hi(uC[q]);
        }
        jA += 8; jB += 8; jC += 8;
    }
    drain2(xwb, adj, lane, jA, eA, a0, a1, jB, eB, c0, c1);
    drain2(xwb, adj, lane, jA, eA, a0, a1, jC, eC, d0, d1);
    drain2(xwb, adj, lane, jB, eB, c0, c1, jC, eC, d0, d1);
    drain1(xwb, adj, lane, jA, eA, a0, a1);
    drain1(xwb, adj, lane, jB, eB, c0, c1);
    drain1(xwb, adj, lane, jC, eC, d0, d1);

    float2 bv = ((const float2*)bias)[lane];
    float di0 = dinv[i0];
    float o0 = fmaxf(fmaf(di0, a0, bv.x), 0.f);
    float o1 = fmaxf(fmaf(di0, a1, bv.y), 0.f);
    float di1 = has1 ? dinv[i1] : 0.f;
    float o2 = has1 ? fmaxf(fmaf(di1, c0, bv.x), 0.f) : 0.f;
    float o3 = has1 ? fmaxf(fmaf(di1, c1, bv.y), 0.f) : 0.f;
    float di2 = has2 ? dinv[i2] : 0.f;
    float o4 = has2 ? fmaxf(fmaf(di2, d0, bv.x), 0.f) : 0.f;
    float o5 = has2 ? fmaxf(fmaf(di2, d1, bv.y), 0.f) : 0.f;

    // classifier partials: lane holds h[i][2*lane], h[i][2*lane+1] for each node
    const float4* W4 = (const float4*)Wfc;          // Wfc is [256][4] row-major
    float4 wa = W4[2 * lane];
    float4 wb = W4[2 * lane + 1];
    float4 wc = W4[128 + 2 * lane];
    float4 wd = W4[129 + 2 * lane];
    float p0 = fmaf(o0, wa.x, o1 * wb.x), p1 = fmaf(o0, wa.y, o1 * wb.y);
    float p2 = fmaf(o0, wa.z, o1 * wb.z), p3 = fmaf(o0, wa.w, o1 * wb.w);
    float q0 = fmaf(o0, wc.x, o1 * wd.x), q1 = fmaf(o0, wc.y, o1 * wd.y);
    float q2 = fmaf(o0, wc.z, o1 * wd.z), q3 = fmaf(o0, wc.w, o1 * wd.w);
    float r0 = fmaf(o2, wa.x, o3 * wb.x), r1 = fmaf(o2, wa.y, o3 * wb.y);
    float r2 = fmaf(o2, wa.z, o3 * wb.z), r3 = fmaf(o2, wa.w, o3 * wb.w);
    float s0 = fmaf(o2, wc.x, o3 * wd.x), s1 = fmaf(o2, wc.y, o3 * wd.y);
    float s2 = fmaf(o2, wc.z, o3 * wd.z), s3 = fmaf(o2, wc.w, o3 * wd.w);
    float t0 = fmaf(o4, wa.x, o5 * wb.x), t1 = fmaf(o4, wa.y, o5 * wb.y);
    float t2 = fmaf(o4, wa.z, o5 * wb.z), t3 = fmaf(o4, wa.w, o5 * wb.w);
    float u0 = fmaf(o4, wc.x, o5 * wd.x), u1 = fmaf(o4, wc.y, o5 * wd.y);
    float u2 = fmaf(o4, wc.z, o5 * wd.z), u3 = fmaf(o4, wc.w, o5 * wd.w);
#pragma unroll
    for (int off = 1; off < 64; off <<= 1) {
        p0 += __shfl_xor(p0, off, 64); p1 += __shfl_xor(p1, off, 64);
        p2 += __shfl_xor(p2, off, 64); p3 += __shfl_xor(p3, off, 64);
        q0 += __shfl_xor(q0, off, 64); q1 += __shfl_xor(q1, off, 64);
        q2 += __shfl_xor(q2, off, 64); q3 += __shfl_xor(q3, off, 64);
        r0 += __shfl_xor(r0, off, 64); r1 += __shfl_xor(r1, off, 64);
        r2 += __shfl_xor(r2, off, 64); r3 += __shfl_xor(r3, off, 64);
        s0 += __shfl_xor(s0, off, 64); s1 += __shfl_xor(s1, off, 64);
        s2 += __shfl_xor(s2, off, 64); s3 += __shfl_xor(s3, off, 64);
        t0 += __shfl_xor(t0, off, 64); t1 += __shfl_xor(t1, off, 64);
        t2 += __shfl_xor(t2, off, 64); t3 += __shfl_xor(t3, off, 64);
        u0 += __shfl_xor(u0, off, 64); u1 += __shfl_xor(u1, off, 64);
        u2 += __shfl_xor(u2, off, 64); u3 += __shfl_xor(u3, off, 64);
    }
    if (lane == 0) {
        float4 bb = *(const float4*)bfc;
        *(float4*)(P1 + (size_t)i0 * 4) = make_float4(p0 + bb.x, p1 + bb.y, p2 + bb.z, p3 + bb.w);
        *(float4*)(P2 + (size_t)i0 * 4) = make_float4(q0, q1, q2, q3);
        if (has1) {
            *(float4*)(P1 + (size_t)i1 * 4) = make_float4(r0 + bb.x, r1 + bb.y, r2 + bb.z, r3 + bb.w);
            *(float4*)(P2 + (size_t)i1 * 4) = make_float4(s0, s1, s2, s3);
        }
        if (has2) {
            *(float4*)(P1 + (size_t)i2 * 4) = make_float4(t0 + bb.x, t1 + bb.y, t2 + bb.z, t3 + bb.w);
            *(float4*)(P2 + (size_t)i2 * 4) = make_float4(u0, u1, u2, u3);
        }
    }
}

// ---------------- edge classifier: one THREAD per edge ----------------

__global__ __launch_bounds__(256) void edge2_kernel(const int* __restrict__ row,
                                                    const int* __restrict__ col,
                                                    const float* __restrict__ P1,
                                                    const float* __restrict__ P2,
                                                    float* __restrict__ out, int E) {
    int e = blockIdx.x * blockDim.x + threadIdx.x;
    if (e >= E) return;
    int r = row[e], c = col[e];
    float4 a = ((const float4*)P1)[r];
    float4 b = ((const float4*)P2)[c];
    float sx = a.x + b.x, sy = a.y + b.y, sz = a.z + b.z, sw = a.w + b.w;
    float m = fmaxf(fmaxf(sx, sy), fmaxf(sz, sw));
    float e0 = expf(sx - m), e1 = expf(sy - m), e2 = expf(sz - m), e3 = expf(sw - m);
    float lse = m + logf(e0 + e1 + e2 + e3);
    *(float4*)(out + (size_t)e * 4) = make_float4(sx - lse, sy - lse, sz - lse, sw - lse);
}

// ---------------- launch ----------------

extern "C" void kernel_launch(void* const* d_in, const int* in_sizes, int n_in,
                              void* d_out, int out_size, void* d_ws, size_t ws_size,
                              hipStream_t stream) {
    const float* x   = (const float*)d_in[0];
    const int*   ei  = (const int*)d_in[1];
    const float* W1  = (const float*)d_in[2];
    const float* b1  = (const float*)d_in[3];
    const float* W2  = (const float*)d_in[4];
    const float* b2  = (const float*)d_in[5];
    const float* Wfc = (const float*)d_in[6];
    const float* bfc = (const float*)d_in[7];
    float* out = (float*)d_out;

    int n = in_sizes[0] / D;        // 50000
    int E = in_sizes[1] / 2;        // 600000
    const int* row = ei;            // edge_index[0]
    const int* col = ei + E;        // edge_index[1]

    int nbScan = (n + SCAN_CHUNK - 1) / SCAN_CHUNK;   // 25

    // workspace layout (all segments 16B-aligned)
    uint16_t* xwb  = (uint16_t*)d_ws;                    // [n][128] bf16 (layer-1 xW, dinv-prescaled)
    uint16_t* xwb2 = xwb + (size_t)n * D;                // [n][128] bf16 (layer-2 xW, dinv-prescaled)
    float*    h    = (float*)(xwb2 + (size_t)n * D);     // [n][128] f32 (layer-1 output)
    int*      cnt  = (int*)(h + (size_t)n * D);          // n
    int*      offs = cnt + n;                            // n+1 (+pad)
    int*      bsum = offs + (n + 4);                     // 64
    int*      adj  = bsum + 64;                          // E
    int*      rnk  = adj + E;                            // E (edge rank within bucket)
    float*    dinv = (float*)(rnk + E);                  // n
    uint16_t* Wph  = (uint16_t*)(dinv + n);              // 2*16384 (layer-major)
    uint16_t* Wpl  = Wph + 2 * 16384;                    // 2*16384
    float*    P1   = (float*)(Wpl + 2 * 16384);          // n*4
    float*    P2   = P1 + (size_t)n * 4;                 // n*4

    int nb_e = (E + 255) / 256;
    int nbG  = (n + 63) / 64;
    int nWaves = (n + 2) / 3;                 // three nodes per wave
    int nbA  = (nWaves + 3) / 4;              // 4 waves per block

    // CSR count (+ W pack; rank captured from atomicAdd return)
    hipMemsetAsync(cnt, 0, (size_t)n * sizeof(int), stream);
    countpack_kernel<<<nb_e, 256, 0, stream>>>(col, cnt, rnk, E, W1, W2, Wph, Wpl);
    scanA_kernel<<<nbScan, 256, 0, stream>>>(cnt, bsum, dinv, n);
    scanC_kernel<<<nbScan, 256, 0, stream>>>(cnt, bsum, offs, n, nbScan);

    // fill (CSR scatter) runs concurrently with layer-1 GEMM in one grid
    fillgemm_kernel<<<nbG + nb_e, 256, 0, stream>>>(row, col, rnk, offs, adj, E,
                                                    x, Wph, Wpl, dinv, xwb, n, nbG);

    // layer-1 aggregation (three nodes/wave, full-row gather) -> h f32
    agg1_kernel<<<nbA, 256, 0, stream>>>((const uint32_t*)xwb, adj, offs, dinv, b1, h, n);

    // layer-2 GEMM
    gemm_kernel<<<nbG, 256, 0, stream>>>(h, Wph + 16384, Wpl + 16384, dinv, xwb2, n);

    // layer-2 aggregation + classifier precompute (three nodes/wave, full-row gather)
    agg2pq_kernel<<<nbA, 256, 0, stream>>>((const uint32_t*)xwb2, adj, offs, dinv, b2,
                                           Wfc, bfc, P1, P2, n);

    // edge classifier
    edge2_kernel<<<nb_e, 256, 0, stream>>>(row, col, P1, P2, out, E);
}

// Round 10
// 231.582 us; speedup vs baseline: 1.0892x; 1.0892x over previous
//
#include <hip/hip_runtime.h>
#include <math.h>
#include <stdint.h>

#define D 128          // feature dim (d_in = d_h = 128)
#define SCAN_CHUNK 2048
#define LDA 136        // LDS row stride in shorts (+8 pad: 16-way -> 2-way bank conflict)

typedef __attribute__((ext_vector_type(8))) short v8s;   // 8 bf16 (4 VGPRs)
typedef __attribute__((ext_vector_type(4))) float v4f;   // MFMA accumulator

// bf16 round-to-nearest-even
static __device__ __forceinline__ uint16_t f2bf(float f) {
    uint32_t u = __float_as_uint(f);
    u = (u + 0x7fff + ((u >> 16) & 1)) >> 16;
    return (uint16_t)u;
}
static __device__ __forceinline__ float bf2f(uint16_t h) { return __uint_as_float((uint32_t)h << 16); }
static __device__ __forceinline__ float bf_lo(uint32_t u) { return __uint_as_float(u << 16); }
static __device__ __forceinline__ float bf_hi(uint32_t u) { return __uint_as_float(u & 0xffff0000u); }

// ---------------- count + rank + W-pack (fused, independent work) ----------------
// rank[e] = edge's slot within its target bucket (atomicAdd return) -> fill has NO atomics.

__global__ void countpack_kernel(const int* __restrict__ col, int* __restrict__ cnt,
                                 int* __restrict__ rnk, int E,
                                 const float* __restrict__ W1, const float* __restrict__ W2,
                                 uint16_t* __restrict__ Wh, uint16_t* __restrict__ Wl) {
    int tid = blockIdx.x * blockDim.x + threadIdx.x;
    if (tid < 2 * 16384) {
        int layer = tid >> 14;
        int li = tid & 16383;
        int j = li & 7, lane = (li >> 3) & 63, f = li >> 9;
        int kstep = f >> 3, tile = f & 7;
        int k = kstep * 32 + ((lane >> 4) * 8) + j;
        int nn = tile * 16 + (lane & 15);
        const float* W = layer ? W2 : W1;
        float v = W[k * 128 + nn];
        uint16_t h = f2bf(v);
        Wh[tid] = h;
        Wl[tid] = f2bf(v - bf2f(h));
    }
    if (tid < E) rnk[tid] = atomicAdd(&cnt[col[tid]], 1);
}

// ---------------- scan phase A: per-chunk sums (+ fused dinv) ----------------
// Multi-block, coalesced. (Single-block variant measured 134 us @0.17% occupancy — do not revisit.)

__global__ __launch_bounds__(256) void scanA_kernel(const int* __restrict__ cnt,
                                                    int* __restrict__ bsum,
                                                    float* __restrict__ dinv, int n) {
    __shared__ int wsum[4];
    int b = blockIdx.x, t = threadIdx.x;
    int base = b * SCAN_CHUNK;
    int s = 0;
#pragma unroll
    for (int k = 0; k < SCAN_CHUNK / 256; k++) {
        int i = base + k * 256 + t;
        if (i < n) {
            int c = cnt[i];
            s += c;
            dinv[i] = rsqrtf((float)c + 1.0f);
        }
    }
#pragma unroll
    for (int off = 32; off > 0; off >>= 1) s += __shfl_xor(s, off, 64);
    if ((t & 63) == 0) wsum[t >> 6] = s;
    __syncthreads();
    if (t == 0) bsum[b] = wsum[0] + wsum[1] + wsum[2] + wsum[3];
}

// ---------------- scan phase C: local exclusive scan, block bases inlined ----------------

__global__ __launch_bounds__(256) void scanC_kernel(const int* __restrict__ cnt,
                                                    const int* __restrict__ bsum,
                                                    int* __restrict__ offs, int n, int nb) {
    __shared__ int stage[SCAN_CHUNK];
    __shared__ int res[SCAN_CHUNK];
    __shared__ int tsum[256];
    __shared__ int sb[64];
    int b = blockIdx.x, t = threadIdx.x;
    if (t < 64) {
        int v = (t < nb) ? bsum[t] : 0;
        int inc = v;
#pragma unroll
        for (int off = 1; off < 64; off <<= 1) {
            int u = __shfl_up(inc, off, 64);
            if (t >= off) inc += u;
        }
        sb[t] = inc;
    }
    int base = b * SCAN_CHUNK;
#pragma unroll
    for (int k = 0; k < SCAN_CHUNK / 256; k++) {
        int i = base + k * 256 + t;
        stage[k * 256 + t] = (i < n) ? cnt[i] : 0;
    }
    __syncthreads();
    int my = 0;
#pragma unroll
    for (int j = 0; j < 8; j++) my += stage[t * 8 + j];
    tsum[t] = my;
    __syncthreads();
    for (int off = 1; off < 256; off <<= 1) {
        int v = (t >= off) ? tsum[t - off] : 0;
        __syncthreads();
        tsum[t] += v;
        __syncthreads();
    }
    int bbase = (b == 0) ? 0 : sb[b - 1];
    int run = tsum[t] - my + bbase;
#pragma unroll
    for (int j = 0; j < 8; j++) {
        res[t * 8 + j] = run;
        run += stage[t * 8 + j];
    }
    __syncthreads();
#pragma unroll
    for (int k = 0; k < SCAN_CHUNK / 256; k++) {
        int i = base + k * 256 + t;
        if (i < n) offs[i] = res[k * 256 + t];
    }
    if (b == gridDim.x - 1 && t == 0) offs[n] = sb[nb - 1];
}

// ---------------- MFMA GEMM body (4 waves, flat [M][128] bf16 C-write) ----------------
// split-bf16 (Markidis): A@W ~= Ah@Wh + Ah@Wl + Al@Wh; result pre-scaled by dinv.

static __device__ __forceinline__ void gemm_body(const uint16_t Ah[][LDA],
                                                 const uint16_t Al[][LDA],
                                                 const uint16_t* __restrict__ Wph,
                                                 const uint16_t* __restrict__ Wpl,
                                                 const float* __restrict__ dinv,
                                                 uint16_t* __restrict__ Cb,
                                                 int base_row, int M, int t) {
    int lane = t & 63, w = t >> 6;
    int m_l = lane & 15, quad = lane >> 4;
    int arow = w * 16 + m_l;

    v4f acc[8];
#pragma unroll
    for (int i = 0; i < 8; i++) acc[i] = (v4f){0.f, 0.f, 0.f, 0.f};

#pragma unroll
    for (int ks = 0; ks < 4; ks++) {
        v8s ah = *(const v8s*)&Ah[arow][ks * 32 + quad * 8];
        v8s al = *(const v8s*)&Al[arow][ks * 32 + quad * 8];
#pragma unroll
        for (int ti = 0; ti < 8; ti++) {
            int f = ks * 8 + ti;
            v8s bh = *(const v8s*)(Wph + ((size_t)(f * 64 + lane)) * 8);
            v8s bl = *(const v8s*)(Wpl + ((size_t)(f * 64 + lane)) * 8);
            acc[ti] = __builtin_amdgcn_mfma_f32_16x16x32_bf16(al, bh, acc[ti], 0, 0, 0);
            acc[ti] = __builtin_amdgcn_mfma_f32_16x16x32_bf16(ah, bl, acc[ti], 0, 0, 0);
            acc[ti] = __builtin_amdgcn_mfma_f32_16x16x32_bf16(ah, bh, acc[ti], 0, 0, 0);
        }
    }

    int rbase = base_row + w * 16 + quad * 4;
#pragma unroll
    for (int reg = 0; reg < 4; reg++) {
        int gr = rbase + reg;
        if (gr < M) {
            float di = dinv[gr];
#pragma unroll
            for (int ti = 0; ti < 8; ti++) {
                Cb[(size_t)gr * D + ti * 16 + m_l] = f2bf(di * acc[ti][reg]);
            }
        }
    }
}

// f32 [M][128] row-major A-tile -> split-bf16 LDS staging (shared by both GEMMs)
static __device__ __forceinline__ void stage_tile(uint16_t Ah[][LDA], uint16_t Al[][LDA],
                                                  const float* __restrict__ A,
                                                  int base_row, int M, int t) {
#pragma unroll
    for (int kk = 0; kk < 8; kk++) {
        int idx = kk * 256 + t;
        int r = idx >> 5;
        int c4 = idx & 31;
        int gr = base_row + r;
        float4 f = (gr < M) ? *(const float4*)(A + (size_t)gr * D + c4 * 4)
                            : make_float4(0.f, 0.f, 0.f, 0.f);
        uint16_t h0 = f2bf(f.x), h1 = f2bf(f.y), h2 = f2bf(f.z), h3 = f2bf(f.w);
        uint16_t l0 = f2bf(f.x - bf2f(h0)), l1 = f2bf(f.y - bf2f(h1));
        uint16_t l2 = f2bf(f.z - bf2f(h2)), l3 = f2bf(f.w - bf2f(h3));
        *(ushort4*)&Ah[r][c4 * 4] = make_ushort4(h0, h1, h2, h3);
        *(ushort4*)&Al[r][c4 * 4] = make_ushort4(l0, l1, l2, l3);
    }
}

// ---------------- fused: CSR fill (block-role split) + layer-1 GEMM ----------------

__global__ __launch_bounds__(256) void fillgemm_kernel(const int* __restrict__ row,
                                                       const int* __restrict__ col,
                                                       const int* __restrict__ rnk,
                                                       const int* __restrict__ offs,
                                                       int* __restrict__ adj, int E,
                                                       const float* __restrict__ A,
                                                       const uint16_t* __restrict__ Wph,
                                                       const uint16_t* __restrict__ Wpl,
                                                       const float* __restrict__ dinv,
                                                       uint16_t* __restrict__ Cb, int M,
                                                       int nbG) {
    __shared__ uint16_t Ah[64][LDA];
    __shared__ uint16_t Al[64][LDA];
    int t = threadIdx.x;

    if (blockIdx.x >= nbG) {   // ---- fill role (atomic-free scatter) ----
        int e = (blockIdx.x - nbG) * 256 + t;
        if (e < E) adj[offs[col[e]] + rnk[e]] = row[e];
        return;
    }

    int base_row = blockIdx.x * 64;
    stage_tile(Ah, Al, A, base_row, M, t);
    __syncthreads();
    gemm_body(Ah, Al, Wph, Wpl, dinv, Cb, base_row, M, t);
}

// ---------------- plain GEMM (layer 2: h -> xwb2) ----------------

__global__ __launch_bounds__(256) void gemm_kernel(const float* __restrict__ A,
                                                   const uint16_t* __restrict__ Wph,
                                                   const uint16_t* __restrict__ Wpl,
                                                   const float* __restrict__ dinv,
                                                   uint16_t* __restrict__ Cb, int M) {
    __shared__ uint16_t Ah[64][LDA];
    __shared__ uint16_t Al[64][LDA];
    int t = threadIdx.x;
    int base_row = blockIdx.x * 64;
    stage_tile(Ah, Al, A, base_row, M, t);
    __syncthreads();
    gemm_body(Ah, Al, Wph, Wpl, dinv, Cb, base_row, M, t);
}

// ---------------- aggregation, layer 1: TWO nodes per wave, full-row gather ----------
// Full-row uint32 loads (64 lanes x 4B = one 256 B row per instruction) — the fastest
// measured gather form. Two nodes per wave with an 8+8 interleaved main loop -> 16
// row-loads (64 lines) in flight per wave at 28 VGPR / 66% occupancy — the measured
// sweet spot of the MLP axis (1-node slower; 3-node @48 VGPR drops occupancy to 38%
// and regresses, R9).

__global__ __launch_bounds__(256) void agg1_kernel(const uint32_t* __restrict__ xwb,
                                                   const int* __restrict__ adj,
                                                   const int* __restrict__ offs,
                                                   const float* __restrict__ dinv,
                                                   const float* __restrict__ bias,
                                                   float* __restrict__ hout, int n) {
    int wave = (int)((blockIdx.x * (size_t)blockDim.x + threadIdx.x) >> 6);
    int lane = threadIdx.x & 63;
    int i0 = wave * 2, i1 = wave * 2 + 1;
    if (i0 >= n) return;
    bool has1 = (i1 < n);

    float a0, a1, c0 = 0.f, c1 = 0.f;
    uint32_t su0 = xwb[(size_t)i0 * (D / 2) + lane];
    a0 = bf_lo(su0); a1 = bf_hi(su0);
    int jA = offs[i0], eA = offs[i0 + 1];
    int jB = 0, eB = 0;
    if (has1) {
        uint32_t su1 = xwb[(size_t)i1 * (D / 2) + lane];
        c0 = bf_lo(su1); c1 = bf_hi(su1);
        jB = offs[i1]; eB = offs[i1 + 1];
    }

    // interleaved main loop: 8 gathers per node, 16 rows in flight
    while (jA + 7 < eA && jB + 7 < eB) {
        int xx[8], yy[8];
#pragma unroll
        for (int q = 0; q < 8; q++) { xx[q] = adj[jA + q]; yy[q] = adj[jB + q]; }
        uint32_t uA[8], uB[8];
#pragma unroll
        for (int q = 0; q < 8; q++) {
            uA[q] = xwb[(size_t)xx[q] * (D / 2) + lane];
            uB[q] = xwb[(size_t)yy[q] * (D / 2) + lane];
        }
#pragma unroll
        for (int q = 0; q < 8; q++) {
            a0 += bf_lo(uA[q]); a1 += bf_hi(uA[q]);
            c0 += bf_lo(uB[q]); c1 += bf_hi(uB[q]);
        }
        jA += 8; jB += 8;
    }
    // drain A
    for (; jA + 7 < eA; jA += 8) {
        int xx[8]; uint32_t uA[8];
#pragma unroll
        for (int q = 0; q < 8; q++) xx[q] = adj[jA + q];
#pragma unroll
        for (int q = 0; q < 8; q++) uA[q] = xwb[(size_t)xx[q] * (D / 2) + lane];
#pragma unroll
        for (int q = 0; q < 8; q++) { a0 += bf_lo(uA[q]); a1 += bf_hi(uA[q]); }
    }
    for (; jA + 3 < eA; jA += 4) {
        int x0 = adj[jA], x1 = adj[jA + 1], x2 = adj[jA + 2], x3 = adj[jA + 3];
        uint32_t u0 = xwb[(size_t)x0 * (D / 2) + lane];
        uint32_t u1 = xwb[(size_t)x1 * (D / 2) + lane];
        uint32_t u2 = xwb[(size_t)x2 * (D / 2) + lane];
        uint32_t u3 = xwb[(size_t)x3 * (D / 2) + lane];
        a0 += bf_lo(u0); a1 += bf_hi(u0);
        a0 += bf_lo(u1); a1 += bf_hi(u1);
        a0 += bf_lo(u2); a1 += bf_hi(u2);
        a0 += bf_lo(u3); a1 += bf_hi(u3);
    }
    for (; jA < eA; jA++) {
        uint32_t u = xwb[(size_t)adj[jA] * (D / 2) + lane];
        a0 += bf_lo(u); a1 += bf_hi(u);
    }
    // drain B
    for (; jB + 7 < eB; jB += 8) {
        int yy[8]; uint32_t uB[8];
#pragma unroll
        for (int q = 0; q < 8; q++) yy[q] = adj[jB + q];
#pragma unroll
        for (int q = 0; q < 8; q++) uB[q] = xwb[(size_t)yy[q] * (D / 2) + lane];
#pragma unroll
        for (int q = 0; q < 8; q++) { c0 += bf_lo(uB[q]); c1 += bf_hi(uB[q]); }
    }
    for (; jB + 3 < eB; jB += 4) {
        int y0 = adj[jB], y1 = adj[jB + 1], y2 = adj[jB + 2], y3 = adj[jB + 3];
        uint32_t u0 = xwb[(size_t)y0 * (D / 2) + lane];
        uint32_t u1 = xwb[(size_t)y1 * (D / 2) + lane];
        uint32_t u2 = xwb[(size_t)y2 * (D / 2) + lane];
        uint32_t u3 = xwb[(size_t)y3 * (D / 2) + lane];
        c0 += bf_lo(u0); c1 += bf_hi(u0);
        c0 += bf_lo(u1); c1 += bf_hi(u1);
        c0 += bf_lo(u2); c1 += bf_hi(u2);
        c0 += bf_lo(u3); c1 += bf_hi(u3);
    }
    for (; jB < eB; jB++) {
        uint32_t u = xwb[(size_t)adj[jB] * (D / 2) + lane];
        c0 += bf_lo(u); c1 += bf_hi(u);
    }

    float2 bv = ((const float2*)bias)[lane];
    float di0 = dinv[i0];
    float o0 = fmaxf(fmaf(di0, a0, bv.x), 0.f);
    float o1 = fmaxf(fmaf(di0, a1, bv.y), 0.f);
    ((float2*)(hout + (size_t)i0 * D))[lane] = make_float2(o0, o1);
    if (has1) {
        float di1 = dinv[i1];
        float o2 = fmaxf(fmaf(di1, c0, bv.x), 0.f);
        float o3 = fmaxf(fmaf(di1, c1, bv.y), 0.f);
        ((float2*)(hout + (size_t)i1 * D))[lane] = make_float2(o2, o3);
    }
}

// ---------------- layer-2 aggregation + classifier precompute, TWO nodes per wave ----
// Same gather; epilogue computes both nodes' 8 classifier dot-products in-register
// (lane holds h[i][2*lane], h[i][2*lane+1]) and reduces 16 values with one 6-stage
// 64-wide butterfly — same shuffle cost PER NODE as the single-node version.

__global__ __launch_bounds__(256) void agg2pq_kernel(const uint32_t* __restrict__ xwb,
                                                     const int* __restrict__ adj,
                                                     const int* __restrict__ offs,
                                                     const float* __restrict__ dinv,
                                                     const float* __restrict__ bias,
                                                     const float* __restrict__ Wfc,
                                                     const float* __restrict__ bfc,
                                                     float* __restrict__ P1,
                                                     float* __restrict__ P2, int n) {
    int wave = (int)((blockIdx.x * (size_t)blockDim.x + threadIdx.x) >> 6);
    int lane = threadIdx.x & 63;
    int i0 = wave * 2, i1 = wave * 2 + 1;
    if (i0 >= n) return;
    bool has1 = (i1 < n);

    float a0, a1, c0 = 0.f, c1 = 0.f;
    uint32_t su0 = xwb[(size_t)i0 * (D / 2) + lane];
    a0 = bf_lo(su0); a1 = bf_hi(su0);
    int jA = offs[i0], eA = offs[i0 + 1];
    int jB = 0, eB = 0;
    if (has1) {
        uint32_t su1 = xwb[(size_t)i1 * (D / 2) + lane];
        c0 = bf_lo(su1); c1 = bf_hi(su1);
        jB = offs[i1]; eB = offs[i1 + 1];
    }

    while (jA + 7 < eA && jB + 7 < eB) {
        int xx[8], yy[8];
#pragma unroll
        for (int q = 0; q < 8; q++) { xx[q] = adj[jA + q]; yy[q] = adj[jB + q]; }
        uint32_t uA[8], uB[8];
#pragma unroll
        for (int q = 0; q < 8; q++) {
            uA[q] = xwb[(size_t)xx[q] * (D / 2) + lane];
            uB[q] = xwb[(size_t)yy[q] * (D / 2) + lane];
        }
#pragma unroll
        for (int q = 0; q < 8; q++) {
            a0 += bf_lo(uA[q]); a1 += bf_hi(uA[q]);
            c0 += bf_lo(uB[q]); c1 += bf_hi(uB[q]);
        }
        jA += 8; jB += 8;
    }
    for (; jA + 7 < eA; jA += 8) {
        int xx[8]; uint32_t uA[8];
#pragma unroll
        for (int q = 0; q < 8; q++) xx[q] = adj[jA + q];
#pragma unroll
        for (int q = 0; q < 8; q++) uA[q] = xwb[(size_t)xx[q] * (D / 2) + lane];
#pragma unroll
        for (int q = 0; q < 8; q++) { a0 += bf_lo(uA[q]); a1 += bf_hi(uA[q]); }
    }
    for (; jA + 3 < eA; jA += 4) {
        int x0 = adj[jA], x1 = adj[jA + 1], x2 = adj[jA + 2], x3 = adj[jA + 3];
        uint32_t u0 = xwb[(size_t)x0 * (D / 2) + lane];
        uint32_t u1 = xwb[(size_t)x1 * (D / 2) + lane];
        uint32_t u2 = xwb[(size_t)x2 * (D / 2) + lane];
        uint32_t u3 = xwb[(size_t)x3 * (D / 2) + lane];
        a0 += bf_lo(u0); a1 += bf_hi(u0);
        a0 += bf_lo(u1); a1 += bf_hi(u1);
        a0 += bf_lo(u2); a1 += bf_hi(u2);
        a0 += bf_lo(u3); a1 += bf_hi(u3);
    }
    for (; jA < eA; jA++) {
        uint32_t u = xwb[(size_t)adj[jA] * (D / 2) + lane];
        a0 += bf_lo(u); a1 += bf_hi(u);
    }
    for (; jB + 7 < eB; jB += 8) {
        int yy[8]; uint32_t uB[8];
#pragma unroll
        for (int q = 0; q < 8; q++) yy[q] = adj[jB + q];
#pragma unroll
        for (int q = 0; q < 8; q++) uB[q] = xwb[(size_t)yy[q] * (D / 2) + lane];
#pragma unroll
        for (int q = 0; q < 8; q++) { c0 += bf_lo(uB[q]); c1 += bf_hi(uB[q]); }
    }
    for (; jB + 3 < eB; jB += 4) {
        int y0 = adj[jB], y1 = adj[jB + 1], y2 = adj[jB + 2], y3 = adj[jB + 3];
        uint32_t u0 = xwb[(size_t)y0 * (D / 2) + lane];
        uint32_t u1 = xwb[(size_t)y1 * (D / 2) + lane];
        uint32_t u2 = xwb[(size_t)y2 * (D / 2) + lane];
        uint32_t u3 = xwb[(size_t)y3 * (D / 2) + lane];
        c0 += bf_lo(u0); c1 += bf_hi(u0);
        c0 += bf_lo(u1); c1 += bf_hi(u1);
        c0 += bf_lo(u2); c1 += bf_hi(u2);
        c0 += bf_lo(u3); c1 += bf_hi(u3);
    }
    for (; jB < eB; jB++) {
        uint32_t u = xwb[(size_t)adj[jB] * (D / 2) + lane];
        c0 += bf_lo(u); c1 += bf_hi(u);
    }

    float2 bv = ((const float2*)bias)[lane];
    float di0 = dinv[i0];
    float o0 = fmaxf(fmaf(di0, a0, bv.x), 0.f);
    float o1 = fmaxf(fmaf(di0, a1, bv.y), 0.f);
    float di1 = has1 ? dinv[i1] : 0.f;
    float o2 = fmaxf(fmaf(di1, c0, bv.x), 0.f);
    float o3 = fmaxf(fmaf(di1, c1, bv.y), 0.f);
    if (!has1) { o2 = 0.f; o3 = 0.f; }

    // classifier partials: lane holds h[i][2*lane], h[i][2*lane+1] for both nodes
    const float4* W4 = (const float4*)Wfc;          // Wfc is [256][4] row-major
    float4 wa = W4[2 * lane];
    float4 wb = W4[2 * lane + 1];
    float4 wc = W4[128 + 2 * lane];
    float4 wd = W4[129 + 2 * lane];
    float p0 = fmaf(o0, wa.x, o1 * wb.x), p1 = fmaf(o0, wa.y, o1 * wb.y);
    float p2 = fmaf(o0, wa.z, o1 * wb.z), p3 = fmaf(o0, wa.w, o1 * wb.w);
    float q0 = fmaf(o0, wc.x, o1 * wd.x), q1 = fmaf(o0, wc.y, o1 * wd.y);
    float q2 = fmaf(o0, wc.z, o1 * wd.z), q3 = fmaf(o0, wc.w, o1 * wd.w);
    float r0 = fmaf(o2, wa.x, o3 * wb.x), r1 = fmaf(o2, wa.y, o3 * wb.y);
    float r2 = fmaf(o2, wa.z, o3 * wb.z), r3 = fmaf(o2, wa.w, o3 * wb.w);
    float s0 = fmaf(o2, wc.x, o3 * wd.x), s1 = fmaf(o2, wc.y, o3 * wd.y);
    float s2 = fmaf(o2, wc.z, o3 * wd.z), s3 = fmaf(o2, wc.w, o3 * wd.w);
#pragma unroll
    for (int off = 1; off < 64; off <<= 1) {
        p0 += __shfl_xor(p0, off, 64);
        p1 += __shfl_xor(p1, off, 64);
        p2 += __shfl_xor(p2, off, 64);
        p3 += __shfl_xor(p3, off, 64);
        q0 += __shfl_xor(q0, off, 64);
        q1 += __shfl_xor(q1, off, 64);
        q2 += __shfl_xor(q2, off, 64);
        q3 += __shfl_xor(q3, off, 64);
        r0 += __shfl_xor(r0, off, 64);
        r1 += __shfl_xor(r1, off, 64);
        r2 += __shfl_xor(r2, off, 64);
        r3 += __shfl_xor(r3, off, 64);
        s0 += __shfl_xor(s0, off, 64);
        s1 += __shfl_xor(s1, off, 64);
        s2 += __shfl_xor(s2, off, 64);
        s3 += __shfl_xor(s3, off, 64);
    }
    if (lane == 0) {
        float4 bb = *(const float4*)bfc;
        *(float4*)(P1 + (size_t)i0 * 4) = make_float4(p0 + bb.x, p1 + bb.y, p2 + bb.z, p3 + bb.w);
        *(float4*)(P2 + (size_t)i0 * 4) = make_float4(q0, q1, q2, q3);
        if (has1) {
            *(float4*)(P1 + (size_t)i1 * 4) = make_float4(r0 + bb.x, r1 + bb.y, r2 + bb.z, r3 + bb.w);
            *(float4*)(P2 + (size_t)i1 * 4) = make_float4(s0, s1, s2, s3);
        }
    }
}

// ---------------- edge classifier: one THREAD per edge ----------------

__global__ __launch_bounds__(256) void edge2_kernel(const int* __restrict__ row,
                                                    const int* __restrict__ col,
                                                    const float* __restrict__ P1,
                                                    const float* __restrict__ P2,
                                                    float* __restrict__ out, int E) {
    int e = blockIdx.x * blockDim.x + threadIdx.x;
    if (e >= E) return;
    int r = row[e], c = col[e];
    float4 a = ((const float4*)P1)[r];
    float4 b = ((const float4*)P2)[c];
    float sx = a.x + b.x, sy = a.y + b.y, sz = a.z + b.z, sw = a.w + b.w;
    float m = fmaxf(fmaxf(sx, sy), fmaxf(sz, sw));
    float e0 = expf(sx - m), e1 = expf(sy - m), e2 = expf(sz - m), e3 = expf(sw - m);
    float lse = m + logf(e0 + e1 + e2 + e3);
    *(float4*)(out + (size_t)e * 4) = make_float4(sx - lse, sy - lse, sz - lse, sw - lse);
}

// ---------------- launch ----------------

extern "C" void kernel_launch(void* const* d_in, const int* in_sizes, int n_in,
                              void* d_out, int out_size, void* d_ws, size_t ws_size,
                              hipStream_t stream) {
    const float* x   = (const float*)d_in[0];
    const int*   ei  = (const int*)d_in[1];
    const float* W1  = (const float*)d_in[2];
    const float* b1  = (const float*)d_in[3];
    const float* W2  = (const float*)d_in[4];
    const float* b2  = (const float*)d_in[5];
    const float* Wfc = (const float*)d_in[6];
    const float* bfc = (const float*)d_in[7];
    float* out = (float*)d_out;

    int n = in_sizes[0] / D;        // 50000
    int E = in_sizes[1] / 2;        // 600000
    const int* row = ei;            // edge_index[0]
    const int* col = ei + E;        // edge_index[1]

    int nbScan = (n + SCAN_CHUNK - 1) / SCAN_CHUNK;   // 25

    // workspace layout (all segments 16B-aligned)
    uint16_t* xwb  = (uint16_t*)d_ws;                    // [n][128] bf16 (layer-1 xW, dinv-prescaled)
    uint16_t* xwb2 = xwb + (size_t)n * D;                // [n][128] bf16 (layer-2 xW, dinv-prescaled)
    float*    h    = (float*)(xwb2 + (size_t)n * D);     // [n][128] f32 (layer-1 output)
    int*      cnt  = (int*)(h + (size_t)n * D);          // n
    int*      offs = cnt + n;                            // n+1 (+pad)
    int*      bsum = offs + (n + 4);                     // 64
    int*      adj  = bsum + 64;                          // E
    int*      rnk  = adj + E;                            // E (edge rank within bucket)
    float*    dinv = (float*)(rnk + E);                  // n
    uint16_t* Wph  = (uint16_t*)(dinv + n);              // 2*16384 (layer-major)
    uint16_t* Wpl  = Wph + 2 * 16384;                    // 2*16384
    float*    P1   = (float*)(Wpl + 2 * 16384);          // n*4
    float*    P2   = P1 + (size_t)n * 4;                 // n*4

    int nb_e = (E + 255) / 256;
    int nbG  = (n + 63) / 64;
    int nWaves = (n + 1) / 2;                 // two nodes per wave
    int nbA  = (nWaves + 3) / 4;              // 4 waves per block

    // CSR count (+ W pack; rank captured from atomicAdd return)
    hipMemsetAsync(cnt, 0, (size_t)n * sizeof(int), stream);
    countpack_kernel<<<nb_e, 256, 0, stream>>>(col, cnt, rnk, E, W1, W2, Wph, Wpl);
    scanA_kernel<<<nbScan, 256, 0, stream>>>(cnt, bsum, dinv, n);
    scanC_kernel<<<nbScan, 256, 0, stream>>>(cnt, bsum, offs, n, nbScan);

    // fill (CSR scatter) runs concurrently with layer-1 GEMM in one grid
    fillgemm_kernel<<<nbG + nb_e, 256, 0, stream>>>(row, col, rnk, offs, adj, E,
                                                    x, Wph, Wpl, dinv, xwb, n, nbG);

    // layer-1 aggregation (two nodes/wave, full-row gather) -> h f32
    agg1_kernel<<<nbA, 256, 0, stream>>>((const uint32_t*)xwb, adj, offs, dinv, b1, h, n);

    // layer-2 GEMM
    gemm_kernel<<<nbG, 256, 0, stream>>>(h, Wph + 16384, Wpl + 16384, dinv, xwb2, n);

    // layer-2 aggregation + classifier precompute (two nodes/wave, full-row gather)
    agg2pq_kernel<<<nbA, 256, 0, stream>>>((const uint32_t*)xwb2, adj, offs, dinv, b2,
                                           Wfc, bfc, P1, P2, n);

    // edge classifier
    edge2_kernel<<<nb_e, 256, 0, stream>>>(row, col, P1, P2, out, E);
}